// Round 26
// baseline (398.064 us; speedup 1.0000x reference)
//
#include <hip/hip_runtime.h>
#include <hip/hip_bf16.h>
#include <stdint.h>

#define N_ROWS 16384
#define E_DIM 512
#define C_DIM 128
#define K_CODES 2048
#define M_BOOKS 4
#define H1_DIM 128
#define H2_DIM 256
#define EPS_V 1e-5f
#define VQ_RT 8

typedef __attribute__((ext_vector_type(8))) short short8v;
typedef __attribute__((ext_vector_type(4))) float f32x4;

#if defined(__has_builtin)
#if __has_builtin(__builtin_amdgcn_global_load_lds)
#define HAVE_GLL 1
#endif
#endif

#ifdef HAVE_GLL
__device__ __forceinline__ void gll16(const void* g, void* l) {
    __builtin_amdgcn_global_load_lds(
        (const __attribute__((address_space(1))) uint32_t*)g,
        (__attribute__((address_space(3))) uint32_t*)l, 16, 0, 0);
}
#endif

__device__ __forceinline__ unsigned int mapmono(float d) {
    unsigned int ub = __float_as_uint(d);
    return (ub & 0x80000000u) ? ~ub : (ub | 0x80000000u);
}
__device__ __forceinline__ float unmapmono(unsigned int u) {
    unsigned int bits = (u & 0x80000000u) ? (u & 0x7FFFFFFFu) : ~u;
    return __uint_as_float(bits);
}

// ---- fused GEMM, 128x128 tile, 8x8 per thread (exact fp32; fallback only) ----
template<int BK, bool BNRELU>
__global__ __launch_bounds__(256, 4) void gemm128(
    const float* __restrict__ A, const float* __restrict__ B,
    const float* __restrict__ bias, const float* __restrict__ bn_g,
    const float* __restrict__ bn_b, const float* __restrict__ bn_m,
    const float* __restrict__ bn_v, float* __restrict__ C,
    int Kd, int Hc, size_t sA, size_t sB, size_t sP, size_t sC)
{
    __shared__ float As[BK][128];
    __shared__ float Bs[BK][128];
    const int z = blockIdx.z;
    A += (size_t)z * sA; B += (size_t)z * sB; bias += (size_t)z * sP;
    if (BNRELU) {
        bn_g += (size_t)z * sP; bn_b += (size_t)z * sP;
        bn_m += (size_t)z * sP; bn_v += (size_t)z * sP;
    }
    const int t = threadIdx.x;
    const int tx = t & 15, ty = t >> 4;
    const int row0 = blockIdx.y * 128, col0 = blockIdx.x * 128;
    const int ar = t & 127, ak = (t >> 7) * 4;
    const int bc = (t & 31) * 4, bk0 = t >> 5;

    float acc[8][8] = {};
    for (int k0 = 0; k0 < Kd; k0 += BK) {
        #pragma unroll
        for (int l = 0; l < BK / 8; ++l) {
            const int lk = ak + l * 8;
            float4 av = *(const float4*)(A + (size_t)(row0 + ar) * Kd + (k0 + lk));
            As[lk+0][ar] = av.x; As[lk+1][ar] = av.y;
            As[lk+2][ar] = av.z; As[lk+3][ar] = av.w;
            const int kb = bk0 + l * 8;
            *(float4*)&Bs[kb][bc] =
                *(const float4*)(B + (size_t)(k0 + kb) * Hc + (col0 + bc));
        }
        __syncthreads();
        #pragma unroll
        for (int kk = 0; kk < BK; ++kk) {
            float a[8], b[8];
            *(float4*)&a[0] = *(const float4*)&As[kk][ty*4];
            *(float4*)&a[4] = *(const float4*)&As[kk][64 + ty*4];
            *(float4*)&b[0] = *(const float4*)&Bs[kk][tx*4];
            *(float4*)&b[4] = *(const float4*)&Bs[kk][64 + tx*4];
            #pragma unroll
            for (int i = 0; i < 8; ++i)
                #pragma unroll
                for (int j = 0; j < 8; ++j)
                    acc[i][j] = fmaf(a[i], b[j], acc[i][j]);
        }
        __syncthreads();
    }
    float bi[8], sc[8], mu[8], be[8];
    #pragma unroll
    for (int j = 0; j < 8; ++j) {
        const int col = col0 + ((j < 4) ? (tx*4 + j) : (64 + tx*4 + j - 4));
        bi[j] = bias[col];
        if (BNRELU) {
            sc[j] = bn_g[col] / sqrtf(bn_v[col] + EPS_V);
            mu[j] = bn_m[col]; be[j] = bn_b[col];
        }
    }
    #pragma unroll
    for (int i = 0; i < 8; ++i) {
        const int row = row0 + ((i < 4) ? (ty*4 + i) : (64 + ty*4 + i - 4));
        float v[8];
        #pragma unroll
        for (int j = 0; j < 8; ++j) {
            v[j] = acc[i][j] + bi[j];
            if (BNRELU) {
                float p = (v[j] - mu[j]) * sc[j];
                asm volatile("" : "+v"(p));
                v[j] = fmaxf(p + be[j], 0.0f);
            }
        }
        float* cp = C + (size_t)z * sC + (size_t)row * Hc + col0;
        *(float4*)(cp + tx*4)      = *(const float4*)&v[0];
        *(float4*)(cp + 64 + tx*4) = *(const float4*)&v[4];
    }
}

// ---- row-wise sum of squares (numpy 8-accumulator pairwise) ----
__global__ __launch_bounds__(256) void rowsq_np(const float* __restrict__ X,
                                                float* __restrict__ out, int rows)
{
    const int r = blockIdx.x * blockDim.x + threadIdx.x;
    if (r >= rows) return;
    const float* p = X + (size_t)r * C_DIM;
    float rr[8];
    #pragma unroll
    for (int j = 0; j < 8; ++j) {
        float v = p[j]; float s2 = v * v;
        asm volatile("" : "+v"(s2));
        rr[j] = s2;
    }
    for (int i = 8; i < C_DIM; i += 8) {
        #pragma unroll
        for (int j = 0; j < 8; ++j) {
            float v = p[i + j]; float s2 = v * v;
            asm volatile("" : "+v"(s2));
            rr[j] = rr[j] + s2;
        }
    }
    out[r] = ((rr[0]+rr[1]) + (rr[2]+rr[3])) + ((rr[4]+rr[5]) + (rr[6]+rr[7]));
}

// ---- split ze rows -> bf16 fragments [m][rt][32 k8][128][8] + zs + eps ----
__global__ __launch_bounds__(256) void split_ze(
    const float* __restrict__ ze, uint16_t* __restrict__ zeAf,
    float* __restrict__ zs, float* __restrict__ eps)
{
    const int m = blockIdx.y;
    const int r = blockIdx.x * 256 + threadIdx.x;
    const size_t g = (size_t)m * N_ROWS + r;
    const float* p = ze + g * C_DIM;
    float a[C_DIM];
    #pragma unroll
    for (int c4 = 0; c4 < C_DIM/4; ++c4) {
        float4 v = *(const float4*)(p + c4*4);
        a[c4*4+0]=v.x; a[c4*4+1]=v.y; a[c4*4+2]=v.z; a[c4*4+3]=v.w;
    }
    {   // zs (numpy 8-acc pairwise) w.r.t. our ze
        float rr[8];
        #pragma unroll
        for (int j = 0; j < 8; ++j) {
            float v = a[j]; float s2 = v*v; asm volatile("" : "+v"(s2)); rr[j]=s2;
        }
        #pragma unroll
        for (int i = 8; i < C_DIM; i += 8)
            #pragma unroll
            for (int j = 0; j < 8; ++j) {
                float v = a[i+j]; float s2 = v*v; asm volatile("" : "+v"(s2));
                rr[j] = rr[j] + s2;
            }
        zs[g] = ((rr[0]+rr[1]) + (rr[2]+rr[3])) + ((rr[4]+rr[5]) + (rr[6]+rr[7]));
    }
    {   // rigorous |approx-exact| bound ~4.6e-5*T, T <= Sabs/2048; use 1e-4
        float sab = 0.0f;
        #pragma unroll
        for (int c = 0; c < C_DIM; ++c) sab += fabsf(a[c]);
        eps[g] = sab * 4.8828125e-4f * 1e-4f + 1e-9f;
    }
    const int rt = r >> 7, rl = r & 127;
    uint16_t* base = zeAf + (size_t)m * 4194304 + ((size_t)rt * 4096 + rl) * 8;
    #pragma unroll
    for (int k8 = 0; k8 < 32; ++k8) {
        uint16_t u[8];
        #pragma unroll
        for (int j = 0; j < 8; ++j) {
            const int c = ((k8 < 16) ? k8 : (k8 - 16)) * 8 + j;
            __hip_bfloat16 h = __float2bfloat16(a[c]);
            if (k8 >= 16) {
                float res = a[c] - __bfloat162float(h);
                h = __float2bfloat16(res);
            }
            u[j] = *(uint16_t*)&h;
        }
        *(float4*)(base + (size_t)k8 * 1024) = *(const float4*)u;
    }
}

// ---- split codebook -> frags; also cbsq (numpy 8-acc) + count=0 ----
__global__ __launch_bounds__(256) void split_cb(
    const float* __restrict__ cb, uint16_t* __restrict__ cbBf,
    float* __restrict__ cbsq, int* __restrict__ count)
{
    const int m = blockIdx.z;
    const int k = blockIdx.x * 256 + threadIdx.x;
    if (m == 0 && k == 0) *count = 0;
    const float* p = cb + ((size_t)m * K_CODES + k) * C_DIM;
    float a[C_DIM];
    #pragma unroll
    for (int c4 = 0; c4 < C_DIM/4; ++c4) {
        float4 v = *(const float4*)(p + c4*4);
        a[c4*4+0]=v.x; a[c4*4+1]=v.y; a[c4*4+2]=v.z; a[c4*4+3]=v.w;
    }
    {
        float rr[8];
        #pragma unroll
        for (int j = 0; j < 8; ++j) {
            float v = a[j]; float s2 = v*v; asm volatile("" : "+v"(s2)); rr[j]=s2;
        }
        #pragma unroll
        for (int i = 8; i < C_DIM; i += 8)
            #pragma unroll
            for (int j = 0; j < 8; ++j) {
                float v = a[i+j]; float s2 = v*v; asm volatile("" : "+v"(s2));
                rr[j] = rr[j] + s2;
            }
        cbsq[(size_t)m * K_CODES + k] =
            ((rr[0]+rr[1]) + (rr[2]+rr[3])) + ((rr[4]+rr[5]) + (rr[6]+rr[7]));
    }
    const int ct = k >> 7, kl = k & 127;
    uint16_t* base = cbBf + (((size_t)m * 16 + ct) * 4096 + kl) * 8;
    #pragma unroll
    for (int k8 = 0; k8 < 32; ++k8) {
        uint16_t u[8];
        #pragma unroll
        for (int j = 0; j < 8; ++j) {
            const int c = ((k8 < 16) ? k8 : (k8 - 16)) * 8 + j;
            __hip_bfloat16 h = __float2bfloat16(a[c]);
            if (k8 >= 16) {
                float res = a[c] - __bfloat162float(h);
                h = __float2bfloat16(res);
            }
            u[j] = *(uint16_t*)&h;
        }
        *(float4*)(base + (size_t)k8 * 1024) = *(const float4*)u;
    }
}

// ---- VQ approx: 64-code B tile (32KB LDS) -> 4 blocks/CU, RT=8, T1 swizzle ----
// Occupancy lever: 66KB->35KB LDS doubles waves/SIMD (2->4) so other waves'
// MFMA covers this wave's top-2 VALU epilogue. kb2 funnel + 2 barriers/rt kept
// (round-24: they bound register lifetime; removing them -> spills).
__global__ __launch_bounds__(256, 4) void vq_mfma(
    const uint16_t* __restrict__ zeAf, const uint16_t* __restrict__ cbBf,
    const float* __restrict__ zs, const float* __restrict__ cbsq,
    unsigned long long* __restrict__ keysB, unsigned long long* __restrict__ keysS)
{
    __shared__ __align__(16) uint16_t Ball[16384];   // 32KB: 64-code B tile
    __shared__ unsigned long long kb2[128][2];

    const int t = threadIdx.x;
    const int l = t & 63, w = t >> 6;
    const int ct2 = blockIdx.y;                       // 64-code tile (0..31)
    const int rt0 = (blockIdx.x & 15) * VQ_RT;
    const int m = blockIdx.x >> 4;
    const int lq = l >> 4, lc = l & 15;

    // source: cbBf[m][ct2>>1] is [32 k8][128 kl][8]; take kl-half (ct2&1)
    const uint16_t* Bg = cbBf + ((size_t)m * 16 + (ct2 >> 1)) * 32768
                       + (size_t)(ct2 & 1) * 512;
#ifdef HAVE_GLL
    #pragma unroll
    for (int i = 0; i < 8; ++i) {
        const int idx = t + i * 256;    // idx = k8*64 + kl
        gll16(Bg + ((size_t)(idx >> 6) * 1024 + (size_t)(idx & 63) * 8),
              Ball + (size_t)idx * 8);
    }
#else
    #pragma unroll
    for (int i = 0; i < 8; ++i) {
        const int idx = t + i * 256;
        *(float4*)(Ball + (size_t)idx * 8) =
            *(const float4*)(Bg + ((size_t)(idx >> 6) * 1024 + (size_t)(idx & 63) * 8));
    }
#endif
    __syncthreads();

    const float* csb = cbsq + (size_t)m * K_CODES + ct2 * 64;

    for (int ri = 0; ri < VQ_RT; ++ri) {
        const int rt = rt0 + ri;
        const uint16_t* Ag = zeAf + (size_t)m * 4194304 + (size_t)rt * 32768;
        f32x4 acc[2][4] = {};
        #pragma unroll
        for (int s = 0; s < 4; ++s) {
            short8v zeh[2], zel[2], cbf[4];
            #pragma unroll
            for (int rc = 0; rc < 2; ++rc) {
                const int row = w*32 + rc*16 + lc;
                zeh[rc] = *(const short8v*)(Ag + ((size_t)(s*4 + lq)*128 + row)*8);
                zel[rc] = *(const short8v*)(Ag + ((size_t)(16 + s*4 + lq)*128 + row)*8);
            }
            #pragma unroll
            for (int c8 = 0; c8 < 4; ++c8)
                cbf[c8] = *(const short8v*)(Ball + ((size_t)(s*4 + lq)*64 + c8*16 + lc)*8);
            #pragma unroll
            for (int rc = 0; rc < 2; ++rc)
                #pragma unroll
                for (int c8 = 0; c8 < 4; ++c8)
                    acc[rc][c8] = __builtin_amdgcn_mfma_f32_16x16x32_bf16(
                        cbf[c8], zeh[rc], acc[rc][c8], 0, 0, 0);   // ze_h*cb_h
            #pragma unroll
            for (int rc = 0; rc < 2; ++rc)
                #pragma unroll
                for (int c8 = 0; c8 < 4; ++c8)
                    acc[rc][c8] = __builtin_amdgcn_mfma_f32_16x16x32_bf16(
                        cbf[c8], zel[rc], acc[rc][c8], 0, 0, 0);   // ze_l*cb_h
            #pragma unroll
            for (int c8 = 0; c8 < 4; ++c8)
                cbf[c8] = *(const short8v*)(Ball + ((size_t)(16 + s*4 + lq)*64 + c8*16 + lc)*8);
            #pragma unroll
            for (int rc = 0; rc < 2; ++rc)
                #pragma unroll
                for (int c8 = 0; c8 < 4; ++c8)
                    acc[rc][c8] = __builtin_amdgcn_mfma_f32_16x16x32_bf16(
                        cbf[c8], zeh[rc], acc[rc][c8], 0, 0, 0);   // ze_h*cb_l
        }

        // lane-local float top-2 over 16 codes, 2-step 4-lane butterfly
        #pragma unroll
        for (int rc = 0; rc < 2; ++rc) {
            const int row = w*32 + rc*16 + lc;
            float bd = 3.4e38f, sd = 3.4e38f;
            int bidx = 0;
            #pragma unroll
            for (int c8 = 0; c8 < 4; ++c8)
                #pragma unroll
                for (int q = 0; q < 4; ++q) {
                    const int cl = c8*16 + lq*4 + q;
                    const float d = fmaf(-2.0f, acc[rc][c8][q], csb[cl]);
                    const float mx = fmaxf(bd, d);
                    sd = fminf(sd, mx);
                    if (d < bd) { bd = d; bidx = ct2*64 + cl; }
                }
            #pragma unroll
            for (int mk = 16; mk < 64; mk <<= 1) {
                const float ob = __shfl_xor(bd, mk);
                const int   oi = __shfl_xor(bidx, mk);
                const float os = __shfl_xor(sd, mk);
                const float mx = fmaxf(bd, ob);
                sd = fminf(fminf(sd, os), mx);
                if (ob < bd) { bd = ob; bidx = oi; }
            }
            if (lq == 0) {
                kb2[row][0] = ((unsigned long long)mapmono(bd) << 32) | (unsigned)bidx;
                kb2[row][1] = ((unsigned long long)mapmono(sd) << 32) | 0xFFFFFFFFu;
            }
        }
        __syncthreads();
        if (t < 128) {
            const unsigned long long b = kb2[t][0];
            const unsigned long long s2v = kb2[t][1];
            const size_t g = (size_t)m * N_ROWS + (size_t)rt*128 + t;
            const unsigned long long old = atomicMin(&keysB[g], b);
            const unsigned long long disp = (b < old) ? old : b;
            const unsigned long long cand = (s2v < disp) ? s2v : disp;
            atomicMin(&keysS[g], cand);
        }
        __syncthreads();   // protect kb2 before next rt
    }
}

// ---- flag: near-tie only (rigorous bound makes exact-dot check redundant) ----
__global__ __launch_bounds__(256) void vq_flag(
    unsigned long long* __restrict__ keysB,
    const unsigned long long* __restrict__ keysS,
    const float* __restrict__ eps, int* __restrict__ list, int* __restrict__ count)
{
    const int m = blockIdx.y;
    const int r = blockIdx.x * 256 + threadIdx.x;
    const size_t g = (size_t)m * N_ROWS + r;
    const float db = unmapmono((unsigned int)(keysB[g] >> 32));
    const float ds2 = unmapmono((unsigned int)(keysS[g] >> 32));
    if (ds2 - db <= 2.0f * eps[g]) {
        keysB[g] = ~0ull;                 // cleanup owns this row now
        const int p = atomicAdd(count, 1);
        list[p] = (int)g;
    }
}

// ---- exact cleanup v3: (row, 1/8-code-slice) work items, 1 code/thread ----
__global__ __launch_bounds__(256) void vq_cleanup3(
    const float* __restrict__ ze, const float* __restrict__ cb,
    const float* __restrict__ zs, const float* __restrict__ cbsq,
    const int* __restrict__ list, const int* __restrict__ count,
    unsigned long long* __restrict__ keysB)
{
    __shared__ float zrow[C_DIM];
    __shared__ unsigned long long red[4];
    const int t = threadIdx.x;
    const int w = t >> 6, l = t & 63;
    const int ntot = (*count) * 8;
    for (int wi = blockIdx.x; wi < ntot; wi += gridDim.x) {
        const int idx = wi >> 3, ks = wi & 7;
        const int g = list[idx];
        const int m = g >> 14;
        __syncthreads();   // zrow reuse guard
        if (t < 32)
            *(float4*)(zrow + t*4) = *(const float4*)(ze + (size_t)g * C_DIM + t*4);
        __syncthreads();
        const float zsr = zs[g];
        const int code = ks * 256 + t;
        const float* cbp = cb + ((size_t)m * K_CODES + code) * C_DIM;
        float acc = 0.0f;
        #pragma unroll
        for (int c4 = 0; c4 < C_DIM/4; ++c4) {
            const float4 b4 = *(const float4*)(cbp + c4*4);
            acc = fmaf(zrow[c4*4+0], b4.x, acc);
            acc = fmaf(zrow[c4*4+1], b4.y, acc);
            acc = fmaf(zrow[c4*4+2], b4.z, acc);
            acc = fmaf(zrow[c4*4+3], b4.w, acc);
        }
        const float tmp = zsr + cbsq[(size_t)m * K_CODES + code];
        float m2a = 2.0f * acc;
        asm volatile("" : "+v"(m2a));
        const float d = tmp - m2a;
        unsigned long long key =
            ((unsigned long long)mapmono(d) << 32) | (unsigned)code;
        #pragma unroll
        for (int off2 = 32; off2 > 0; off2 >>= 1) {
            const unsigned long long o = __shfl_down(key, off2);
            key = (o < key) ? o : key;
        }
        if (l == 0) red[w] = key;
        __syncthreads();
        if (t == 0) {
            unsigned long long b = red[0];
            b = (red[1] < b) ? red[1] : b;
            b = (red[2] < b) ? red[2] : b;
            b = (red[3] < b) ? red[3] : b;
            atomicMin(&keysB[g], b);
        }
    }
}

// ---- split weights W[(m)][Kd][Hc] -> frags [m][Hc/64][Kd/4][64][8] ----
__global__ __launch_bounds__(256) void split_wB(
    const float* __restrict__ W, uint16_t* __restrict__ Wf, int Kd, int Hc)
{
    const int z = blockIdx.z;
    W += (size_t)z * Kd * Hc;
    Wf += (size_t)z * Kd * Hc * 2;
    const int ct = blockIdx.x, k8 = blockIdx.y;
    const int Sh = Kd / 8, S = Kd / 4;
    const int t = threadIdx.x;
    #pragma unroll
    for (int e0 = 0; e0 < 2; ++e0) {
        const int e = t + e0 * 256;
        const int h = e >> 3, j = e & 7;
        const float v = W[(size_t)(k8*8 + j) * Hc + ct*64 + h];
        __hip_bfloat16 hi = __float2bfloat16(v);
        float res = v - __bfloat162float(hi);
        __hip_bfloat16 lo = __float2bfloat16(res);
        Wf[(((size_t)ct*S + k8)*64 + h)*8 + j]      = *(uint16_t*)&hi;
        Wf[(((size_t)ct*S + Sh + k8)*64 + h)*8 + j] = *(uint16_t*)&lo;
    }
}

// ---- strided/batched GEMM via split-bf16 MFMA (A fp32 split inline) ----
template<bool BNRELU>
__global__ __launch_bounds__(256, 3) void mfma_fused(
    const float* __restrict__ A, const uint16_t* __restrict__ Wf,
    const float* __restrict__ bias, const float* __restrict__ bn_g,
    const float* __restrict__ bn_b, const float* __restrict__ bn_m,
    const float* __restrict__ bn_v, float* __restrict__ C, int Kd, int Hc,
    size_t sA, size_t sWf, size_t sP, size_t sC)
{
    __shared__ __align__(16) uint16_t Ah[4096], Al[4096], Bh[2048], Bl[2048];
    const int z = blockIdx.z;
    A += (size_t)z * sA; Wf += (size_t)z * sWf; bias += (size_t)z * sP;
    if (BNRELU) {
        bn_g += (size_t)z * sP; bn_b += (size_t)z * sP;
        bn_m += (size_t)z * sP; bn_v += (size_t)z * sP;
    }
    C += (size_t)z * sC;

    const int t = threadIdx.x;
    const int l = t & 63, w = t >> 6;
    const int kq = l >> 4, lc = l & 15;
    const int row0 = blockIdx.y * 128, col0 = blockIdx.x * 64;
    const int Sh = Kd / 8, S = Kd / 4;
    const uint16_t* Wct = Wf + (size_t)blockIdx.x * S * 512;

    f32x4 acc[2][4] = {};
    const int arow = t & 127, khalf = t >> 7;
    for (int ks = 0; ks < Kd / 32; ++ks) {
        const float* ap = A + (size_t)(row0 + arow) * Kd + ks*32 + khalf*16;
        float fa[16];
        *(float4*)&fa[0]  = *(const float4*)(ap);
        *(float4*)&fa[4]  = *(const float4*)(ap + 4);
        *(float4*)&fa[8]  = *(const float4*)(ap + 8);
        *(float4*)&fa[12] = *(const float4*)(ap + 12);
        uint16_t ah[16], al16[16];
        #pragma unroll
        for (int i = 0; i < 16; ++i) {
            __hip_bfloat16 h = __float2bfloat16(fa[i]);
            float res = fa[i] - __bfloat162float(h);
            __hip_bfloat16 lo = __float2bfloat16(res);
            ah[i] = *(uint16_t*)&h; al16[i] = *(uint16_t*)&lo;
        }
        #pragma unroll
        for (int kql = 0; kql < 2; ++kql) {
            const int kq_ = khalf*2 + kql;
            *(float4*)(Ah + ((size_t)kq_*128 + arow)*8) = *(const float4*)&ah[kql*8];
            *(float4*)(Al + ((size_t)kq_*128 + arow)*8) = *(const float4*)&al16[kql*8];
        }
        {
            const int sec = t >> 6, off = (t & 63) * 8;
            *(float4*)(Bh + (size_t)sec*512 + off) =
                *(const float4*)(Wct + ((size_t)(ks*4 + sec))*512 + off);
            *(float4*)(Bl + (size_t)sec*512 + off) =
                *(const float4*)(Wct + ((size_t)(Sh + ks*4 + sec))*512 + off);
        }
        __syncthreads();
        short8v afh[2], afl[2], bfh[4], bfl[4];
        #pragma unroll
        for (int r2 = 0; r2 < 2; ++r2) {
            afh[r2] = *(const short8v*)(Ah + ((size_t)kq*128 + w*32 + r2*16 + lc)*8);
            afl[r2] = *(const short8v*)(Al + ((size_t)kq*128 + w*32 + r2*16 + lc)*8);
        }
        #pragma unroll
        for (int c4 = 0; c4 < 4; ++c4) {
            bfh[c4] = *(const short8v*)(Bh + ((size_t)kq*64 + c4*16 + lc)*8);
            bfl[c4] = *(const short8v*)(Bl + ((size_t)kq*64 + c4*16 + lc)*8);
        }
        #pragma unroll
        for (int r2 = 0; r2 < 2; ++r2)
            #pragma unroll
            for (int c4 = 0; c4 < 4; ++c4) {
                acc[r2][c4] = __builtin_amdgcn_mfma_f32_16x16x32_bf16(
                    afh[r2], bfh[c4], acc[r2][c4], 0, 0, 0);
                acc[r2][c4] = __builtin_amdgcn_mfma_f32_16x16x32_bf16(
                    afl[r2], bfh[c4], acc[r2][c4], 0, 0, 0);
                acc[r2][c4] = __builtin_amdgcn_mfma_f32_16x16x32_bf16(
                    afh[r2], bfl[c4], acc[r2][c4], 0, 0, 0);
            }
        __syncthreads();
    }
    #pragma unroll
    for (int c4 = 0; c4 < 4; ++c4) {
        const int col = col0 + c4*16 + lc;
        const float bi = bias[col];
        float sc = 0.f, mu = 0.f, be = 0.f;
        if (BNRELU) {
            sc = bn_g[col] / sqrtf(bn_v[col] + EPS_V);
            mu = bn_m[col]; be = bn_b[col];
        }
        #pragma unroll
        for (int r2 = 0; r2 < 2; ++r2)
            #pragma unroll
            for (int q = 0; q < 4; ++q) {
                const int row = row0 + w*32 + r2*16 + kq*4 + q;
                float v = acc[r2][c4][q] + bi;
                if (BNRELU) v = fmaxf((v - mu) * sc + be, 0.0f);
                C[(size_t)row * Hc + col] = v;
            }
    }
}

// ---- old exact tiled VQ (round-5) — fallback when ws too small ----
__global__ __launch_bounds__(256, 4) void vq_argmin(
    const float* __restrict__ ze, const float* __restrict__ cb,
    const float* __restrict__ ze_sq, const float* __restrict__ cb_sq,
    unsigned long long* __restrict__ keys)
{
    __shared__ __align__(16) char smem_raw[32768];
    float* As = (float*)smem_raw;
    float* Bs = As + 32*128;
    unsigned long long* kb = (unsigned long long*)smem_raw;
    const int m = blockIdx.z;
    const float* Zm  = ze + (size_t)m * N_ROWS * C_DIM;
    const float* Bm  = cb + (size_t)m * K_CODES * C_DIM;
    const float* zsm = ze_sq + (size_t)m * N_ROWS;
    const float* csm = cb_sq + (size_t)m * K_CODES;
    const int t = threadIdx.x;
    const int tx = t & 15, ty = t >> 4;
    const int row0 = blockIdx.y * 128, col0 = blockIdx.x * 128;
    const int ar = t & 127, ak = (t >> 7) * 4;
    float acc[8][8] = {};
    for (int k0 = 0; k0 < C_DIM; k0 += 32) {
        #pragma unroll
        for (int l = 0; l < 4; ++l) {
            const int lk = ak + l * 8;
            float4 av = *(const float4*)(Zm + (size_t)(row0 + ar) * C_DIM + (k0 + lk));
            As[(lk+0)*128+ar] = av.x; As[(lk+1)*128+ar] = av.y;
            As[(lk+2)*128+ar] = av.z; As[(lk+3)*128+ar] = av.w;
            float4 bv = *(const float4*)(Bm + (size_t)(col0 + ar) * C_DIM + (k0 + lk));
            Bs[(lk+0)*128+ar] = bv.x; Bs[(lk+1)*128+ar] = bv.y;
            Bs[(lk+2)*128+ar] = bv.z; Bs[(lk+3)*128+ar] = bv.w;
        }
        __syncthreads();
        #pragma unroll
        for (int kk = 0; kk < 32; ++kk) {
            float a[8], b[8];
            *(float4*)&a[0] = *(const float4*)&As[kk*128 + ty*4];
            *(float4*)&a[4] = *(const float4*)&As[kk*128 + 64 + ty*4];
            *(float4*)&b[0] = *(const float4*)&Bs[kk*128 + tx*4];
            *(float4*)&b[4] = *(const float4*)&Bs[kk*128 + 64 + tx*4];
            #pragma unroll
            for (int i = 0; i < 8; ++i)
                #pragma unroll
                for (int j = 0; j < 8; ++j)
                    acc[i][j] = fmaf(a[i], b[j], acc[i][j]);
        }
        __syncthreads();
    }
    unsigned long long mykey[8];
    #pragma unroll
    for (int i = 0; i < 8; ++i) {
        const int rloc = (i < 4) ? (ty*4 + i) : (64 + ty*4 + i - 4);
        const float zsv = zsm[row0 + rloc];
        unsigned long long bk = ~0ull;
        #pragma unroll
        for (int j = 0; j < 8; ++j) {
            const int code = col0 + ((j < 4) ? (tx*4 + j) : (64 + tx*4 + j - 4));
            const float d = (zsv + csm[code]) - 2.0f * acc[i][j];
            const unsigned long long key =
                ((unsigned long long)mapmono(d) << 32) | (unsigned)code;
            bk = (key < bk) ? key : bk;
        }
        mykey[i] = bk;
    }
    __syncthreads();
    #pragma unroll
    for (int i = 0; i < 8; ++i) {
        const int rloc = (i < 4) ? (ty*4 + i) : (64 + ty*4 + i - 4);
        kb[rloc*17 + tx] = mykey[i];
    }
    __syncthreads();
    if (t < 128) {
        unsigned long long bk = kb[t*17];
        #pragma unroll
        for (int k2 = 1; k2 < 16; ++k2) {
            const unsigned long long k = kb[t*17 + k2];
            bk = (k < bk) ? k : bk;
        }
        atomicMin(&keys[(size_t)m * N_ROWS + row0 + t], bk);
    }
}

// ---- gather chosen codes: ce (fp32 out) + zq = sum_m ce ----
__global__ __launch_bounds__(256) void gather_ce_zq(
    const unsigned long long* __restrict__ keys, const float* __restrict__ cb,
    float* __restrict__ ce_out, float* __restrict__ zq)
{
    const int gid = blockIdx.x * 256 + threadIdx.x;
    const int n = gid >> 7, c = gid & 127;
    float s = 0.0f;
    #pragma unroll
    for (int m = 0; m < M_BOOKS; ++m) {
        const int idx = (int)(keys[(size_t)m * N_ROWS + n] & 0xFFFFFFFFull);
        const float v = cb[((size_t)m * K_CODES + idx) * C_DIM + c];
        ce_out[((size_t)m * N_ROWS + n) * (size_t)C_DIM + c] = v;
        s += v;
    }
    zq[gid] = s;
}

extern "C" void kernel_launch(void* const* d_in, const int* in_sizes, int n_in,
                              void* d_out, int out_size, void* d_ws, size_t ws_size,
                              hipStream_t stream)
{
    const float* x   = (const float*)d_in[0];
    const float* eW1 = (const float*)d_in[1];
    const float* eb1 = (const float*)d_in[2];
    const float* g1  = (const float*)d_in[3];
    const float* b1  = (const float*)d_in[4];
    const float* m1  = (const float*)d_in[5];
    const float* v1  = (const float*)d_in[6];
    const float* eW2 = (const float*)d_in[7];
    const float* eb2 = (const float*)d_in[8];
    const float* g2  = (const float*)d_in[9];
    const float* b2  = (const float*)d_in[10];
    const float* m2  = (const float*)d_in[11];
    const float* v2  = (const float*)d_in[12];
    const float* eW3 = (const float*)d_in[13];
    const float* eb3 = (const float*)d_in[14];
    const float* cb  = (const float*)d_in[15];
    const float* dW1 = (const float*)d_in[16];
    const float* db1 = (const float*)d_in[17];
    const float* dg1 = (const float*)d_in[18];
    const float* dbb1= (const float*)d_in[19];
    const float* dm1 = (const float*)d_in[20];
    const float* dv1 = (const float*)d_in[21];
    const float* dW2 = (const float*)d_in[22];
    const float* db2 = (const float*)d_in[23];
    const float* dg2 = (const float*)d_in[24];
    const float* dbb2= (const float*)d_in[25];
    const float* dm2 = (const float*)d_in[26];
    const float* dv2 = (const float*)d_in[27];
    const float* dW3 = (const float*)d_in[28];
    const float* db3 = (const float*)d_in[29];

    float* out_xhat = (float*)d_out;
    float* out_ze   = out_xhat + (size_t)N_ROWS * E_DIM;
    float* out_ce   = out_ze + (size_t)M_BOOKS * N_ROWS * C_DIM;

    float* ws = (float*)d_ws;
    const size_t h1N1 = (size_t)N_ROWS * H1_DIM;
    const size_t h2N1 = (size_t)N_ROWS * H2_DIM;

    // floats needed by batched VQ + all weight-frag machinery
    const size_t vqNeedF = 8192 + 65536 + 65536 + 8388608 + 1048576
                         + 131072 + 131072 + 65536 + 16
                         + 32768 + 32768 + 65536
                         + 524288 + 131072 + 131072;
    const bool tierA = ws_size >= ((size_t)M_BOOKS*(h1N1+h2N1) + vqNeedF + 64) * 4;
    const bool tierB = ws_size >= ((h1N1+h2N1) + vqNeedF + 64) * 4;

    dim3 blk(256, 1, 1);

    if (tierB) {
        size_t off = 0;
        float* h1 = ws; off += (tierA ? M_BOOKS : 1) * h1N1;
        float* h2 = ws + off; off += (tierA ? M_BOOKS : 1) * h2N1;
        float* cbsq = ws + off; off += 8192;
        float* zsb = ws + off; off += 65536;
        float* epsb = ws + off; off += 65536;
        uint16_t* zeAf = (uint16_t*)(ws + off); off += 8388608;
        uint16_t* cbBf = (uint16_t*)(ws + off); off += 1048576;
        unsigned long long* keysB = (unsigned long long*)(ws + off); off += 131072;
        unsigned long long* keysS = (unsigned long long*)(ws + off); off += 131072;
        int* list = (int*)(ws + off); off += 65536;
        int* count = (int*)(ws + off); off += 16;
        uint16_t* w1f = (uint16_t*)(ws + off); off += 32768;
        uint16_t* w2f = (uint16_t*)(ws + off); off += 32768;
        uint16_t* w3f = (uint16_t*)(ws + off); off += 65536;
        uint16_t* we1f = (uint16_t*)(ws + off); off += 524288;
        uint16_t* we2f = (uint16_t*)(ws + off); off += 131072;
        uint16_t* we3f = (uint16_t*)(ws + off); off += 131072;
        float* zq = h1; float* d1 = h2; float* d2 = h1;

        // prep (independent of encoders)
        split_cb<<<dim3(K_CODES/256, 1, M_BOOKS), blk, 0, stream>>>(cb, cbBf, cbsq, count);
        split_wB<<<dim3(H1_DIM/64, E_DIM/8, M_BOOKS), blk, 0, stream>>>(eW1, we1f, E_DIM, H1_DIM);
        split_wB<<<dim3(H2_DIM/64, H1_DIM/8, M_BOOKS), blk, 0, stream>>>(eW2, we2f, H1_DIM, H2_DIM);
        split_wB<<<dim3(C_DIM/64, H2_DIM/8, M_BOOKS), blk, 0, stream>>>(eW3, we3f, H2_DIM, C_DIM);
        split_wB<<<dim3(H2_DIM/64, C_DIM/8, 1), blk, 0, stream>>>(dW1, w1f, C_DIM, H2_DIM);
        split_wB<<<dim3(H1_DIM/64, H2_DIM/8, 1), blk, 0, stream>>>(dW2, w2f, H2_DIM, H1_DIM);
        split_wB<<<dim3(E_DIM/64, H1_DIM/8, 1), blk, 0, stream>>>(dW3, w3f, H1_DIM, E_DIM);
        hipMemsetAsync((void*)keysB, 0xFF, (size_t)M_BOOKS * N_ROWS * 8 * 2, stream);

        const int nz = tierA ? M_BOOKS : 1;
        const int nloop = tierA ? 1 : M_BOOKS;
        for (int p = 0; p < nloop; ++p) {
            const size_t mb = tierA ? 0 : (size_t)p;
            mfma_fused<true><<<dim3(H1_DIM/64, N_ROWS/128, nz), blk, 0, stream>>>(
                x, we1f + mb*(size_t)E_DIM*H1_DIM*2,
                eb1 + mb*H1_DIM, g1 + mb*H1_DIM, b1 + mb*H1_DIM, m1 + mb*H1_DIM, v1 + mb*H1_DIM,
                h1, E_DIM, H1_DIM,
                0, (size_t)E_DIM*H1_DIM*2, H1_DIM, h1N1);
            mfma_fused<true><<<dim3(H2_DIM/64, N_ROWS/128, nz), blk, 0, stream>>>(
                h1, we2f + mb*(size_t)H1_DIM*H2_DIM*2,
                eb2 + mb*H2_DIM, g2 + mb*H2_DIM, b2 + mb*H2_DIM, m2 + mb*H2_DIM, v2 + mb*H2_DIM,
                h2, H1_DIM, H2_DIM,
                h1N1, (size_t)H1_DIM*H2_DIM*2, H2_DIM, h2N1);
            mfma_fused<false><<<dim3(C_DIM/64, N_ROWS/128, nz), blk, 0, stream>>>(
                h2, we3f + mb*(size_t)H2_DIM*C_DIM*2,
                eb3 + mb*C_DIM, nullptr, nullptr, nullptr, nullptr,
                out_ze + mb*(size_t)N_ROWS*C_DIM, H2_DIM, C_DIM,
                h2N1, (size_t)H2_DIM*C_DIM*2, C_DIM, (size_t)N_ROWS*C_DIM);
        }

        split_ze<<<dim3(N_ROWS/256, M_BOOKS), blk, 0, stream>>>(out_ze, zeAf, zsb, epsb);
        vq_mfma<<<dim3(16 * M_BOOKS, K_CODES/64, 1), blk, 0, stream>>>(
            zeAf, cbBf, zsb, cbsq, keysB, keysS);
        vq_flag<<<dim3(N_ROWS/256, M_BOOKS), blk, 0, stream>>>(
            keysB, keysS, epsb, list, count);
        vq_cleanup3<<<dim3(2048), blk, 0, stream>>>(
            out_ze, cb, zsb, cbsq, list, count, keysB);

        gather_ce_zq<<<dim3((N_ROWS*C_DIM)/256), blk, 0, stream>>>(keysB, cb, out_ce, zq);
        mfma_fused<true><<<dim3(H2_DIM/64, N_ROWS/128, 1), blk, 0, stream>>>(
            zq, w1f, db1, dg1, dbb1, dm1, dv1, d1, C_DIM, H2_DIM, 0, 0, 0, 0);
        mfma_fused<true><<<dim3(H1_DIM/64, N_ROWS/128, 1), blk, 0, stream>>>(
            d1, w2f, db2, dg2, dbb2, dm2, dv2, d2, H2_DIM, H1_DIM, 0, 0, 0, 0);
        mfma_fused<false><<<dim3(E_DIM/64, N_ROWS/128, 1), blk, 0, stream>>>(
            d2, w3f, db3, nullptr, nullptr, nullptr, nullptr,
            out_xhat, H1_DIM, E_DIM, 0, 0, 0, 0);
        return;
    }

    // ---- fallback: round-5 exact path ----
    {
        const size_t smallN = (size_t)M_BOOKS*N_ROWS + (size_t)M_BOOKS*K_CODES
                            + 2 + 2*(size_t)M_BOOKS*N_ROWS;
        const size_t fullFloats = (size_t)M_BOOKS*(h1N1 + h2N1) + smallN;
        const bool fM = ws_size >= fullFloats * sizeof(float) + 256;
        size_t off = 0;
        float* h1 = ws; off += (fM ? M_BOOKS : 1) * h1N1;
        float* h2 = ws + off; off += (fM ? M_BOOKS : 1) * h2N1;
        float* zesq = ws + off; off += (size_t)M_BOOKS * N_ROWS;
        float* cbsq = ws + off; off += (size_t)M_BOOKS * K_CODES;
        off = (off + 1) & ~(size_t)1;
        unsigned long long* keys = (unsigned long long*)(ws + off);
        float* zq = h1; float* d1 = h2; float* d2 = h1;
        hipMemsetAsync((void*)keys, 0xFF, (size_t)M_BOOKS * N_ROWS * 8, stream);
        const int nz = fM ? M_BOOKS : 1;
        const int nloop = fM ? 1 : M_BOOKS;
        for (int p = 0; p < nloop; ++p) {
            const size_t mb = fM ? 0 : (size_t)p;
            gemm128<32, true><<<dim3(H1_DIM/128, N_ROWS/128, nz), blk, 0, stream>>>(
                x, eW1 + mb*(size_t)E_DIM*H1_DIM,
                eb1 + mb*H1_DIM, g1 + mb*H1_DIM, b1 + mb*H1_DIM, m1 + mb*H1_DIM, v1 + mb*H1_DIM,
                h1, E_DIM, H1_DIM, 0, (size_t)E_DIM*H1_DIM, H1_DIM, h1N1);
            gemm128<32, true><<<dim3(H2_DIM/128, N_ROWS/128, nz), blk, 0, stream>>>(
                h1, eW2 + mb*(size_t)H1_DIM*H2_DIM,
                eb2 + mb*H2_DIM, g2 + mb*H2_DIM, b2 + mb*H2_DIM, m2 + mb*H2_DIM, v2 + mb*H2_DIM,
                h2, H1_DIM, H2_DIM, h1N1, (size_t)H1_DIM*H2_DIM, H2_DIM, h2N1);
            gemm128<32, false><<<dim3(C_DIM/128, N_ROWS/128, nz), blk, 0, stream>>>(
                h2, eW3 + mb*(size_t)H2_DIM*C_DIM,
                eb3 + mb*C_DIM, nullptr, nullptr, nullptr, nullptr,
                out_ze + mb*(size_t)N_ROWS*C_DIM, H2_DIM, C_DIM,
                h2N1, (size_t)H2_DIM*C_DIM, C_DIM, (size_t)N_ROWS*C_DIM);
        }
        rowsq_np<<<dim3((M_BOOKS*N_ROWS)/256), blk, 0, stream>>>(out_ze, zesq, M_BOOKS*N_ROWS);
        rowsq_np<<<dim3((M_BOOKS*K_CODES)/256), blk, 0, stream>>>(cb, cbsq, M_BOOKS*K_CODES);
        vq_argmin<<<dim3(K_CODES/128, N_ROWS/128, M_BOOKS), blk, 0, stream>>>(
            out_ze, cb, zesq, cbsq, keys);
        gather_ce_zq<<<dim3((N_ROWS*C_DIM)/256), blk, 0, stream>>>(keys, cb, out_ce, zq);
        gemm128<32, true><<<dim3(H2_DIM/128, N_ROWS/128, 1), blk, 0, stream>>>(
            zq, dW1, db1, dg1, dbb1, dm1, dv1, d1, C_DIM, H2_DIM, 0, 0, 0, 0);
        gemm128<32, true><<<dim3(H1_DIM/128, N_ROWS/128, 1), blk, 0, stream>>>(
            d1, dW2, db2, dg2, dbb2, dm2, dv2, d2, H2_DIM, H1_DIM, 0, 0, 0, 0);
        gemm128<32, false><<<dim3(E_DIM/128, N_ROWS/128, 1), blk, 0, stream>>>(
            d2, dW3, db3, nullptr, nullptr, nullptr, nullptr,
            out_xhat, H1_DIM, E_DIM, 0, 0, 0, 0);
    }
}

// Round 27
// 352.083 us; speedup vs baseline: 1.1306x; 1.1306x over previous
//
#include <hip/hip_runtime.h>
#include <hip/hip_bf16.h>
#include <stdint.h>

#define N_ROWS 16384
#define E_DIM 512
#define C_DIM 128
#define K_CODES 2048
#define M_BOOKS 4
#define H1_DIM 128
#define H2_DIM 256
#define EPS_V 1e-5f
#define VQ_RT 8

typedef __attribute__((ext_vector_type(8))) short short8v;
typedef __attribute__((ext_vector_type(4))) float f32x4;

#if defined(__has_builtin)
#if __has_builtin(__builtin_amdgcn_global_load_lds)
#define HAVE_GLL 1
#endif
#endif

#ifdef HAVE_GLL
__device__ __forceinline__ void gll16(const void* g, void* l) {
    __builtin_amdgcn_global_load_lds(
        (const __attribute__((address_space(1))) uint32_t*)g,
        (__attribute__((address_space(3))) uint32_t*)l, 16, 0, 0);
}
#endif

__device__ __forceinline__ unsigned int mapmono(float d) {
    unsigned int ub = __float_as_uint(d);
    return (ub & 0x80000000u) ? ~ub : (ub | 0x80000000u);
}
__device__ __forceinline__ float unmapmono(unsigned int u) {
    unsigned int bits = (u & 0x80000000u) ? (u & 0x7FFFFFFFu) : ~u;
    return __uint_as_float(bits);
}

// ---- fused GEMM, 128x128 tile, 8x8 per thread (exact fp32; fallback only) ----
template<int BK, bool BNRELU>
__global__ __launch_bounds__(256, 4) void gemm128(
    const float* __restrict__ A, const float* __restrict__ B,
    const float* __restrict__ bias, const float* __restrict__ bn_g,
    const float* __restrict__ bn_b, const float* __restrict__ bn_m,
    const float* __restrict__ bn_v, float* __restrict__ C,
    int Kd, int Hc, size_t sA, size_t sB, size_t sP, size_t sC)
{
    __shared__ float As[BK][128];
    __shared__ float Bs[BK][128];
    const int z = blockIdx.z;
    A += (size_t)z * sA; B += (size_t)z * sB; bias += (size_t)z * sP;
    if (BNRELU) {
        bn_g += (size_t)z * sP; bn_b += (size_t)z * sP;
        bn_m += (size_t)z * sP; bn_v += (size_t)z * sP;
    }
    const int t = threadIdx.x;
    const int tx = t & 15, ty = t >> 4;
    const int row0 = blockIdx.y * 128, col0 = blockIdx.x * 128;
    const int ar = t & 127, ak = (t >> 7) * 4;
    const int bc = (t & 31) * 4, bk0 = t >> 5;

    float acc[8][8] = {};
    for (int k0 = 0; k0 < Kd; k0 += BK) {
        #pragma unroll
        for (int l = 0; l < BK / 8; ++l) {
            const int lk = ak + l * 8;
            float4 av = *(const float4*)(A + (size_t)(row0 + ar) * Kd + (k0 + lk));
            As[lk+0][ar] = av.x; As[lk+1][ar] = av.y;
            As[lk+2][ar] = av.z; As[lk+3][ar] = av.w;
            const int kb = bk0 + l * 8;
            *(float4*)&Bs[kb][bc] =
                *(const float4*)(B + (size_t)(k0 + kb) * Hc + (col0 + bc));
        }
        __syncthreads();
        #pragma unroll
        for (int kk = 0; kk < BK; ++kk) {
            float a[8], b[8];
            *(float4*)&a[0] = *(const float4*)&As[kk][ty*4];
            *(float4*)&a[4] = *(const float4*)&As[kk][64 + ty*4];
            *(float4*)&b[0] = *(const float4*)&Bs[kk][tx*4];
            *(float4*)&b[4] = *(const float4*)&Bs[kk][64 + tx*4];
            #pragma unroll
            for (int i = 0; i < 8; ++i)
                #pragma unroll
                for (int j = 0; j < 8; ++j)
                    acc[i][j] = fmaf(a[i], b[j], acc[i][j]);
        }
        __syncthreads();
    }
    float bi[8], sc[8], mu[8], be[8];
    #pragma unroll
    for (int j = 0; j < 8; ++j) {
        const int col = col0 + ((j < 4) ? (tx*4 + j) : (64 + tx*4 + j - 4));
        bi[j] = bias[col];
        if (BNRELU) {
            sc[j] = bn_g[col] / sqrtf(bn_v[col] + EPS_V);
            mu[j] = bn_m[col]; be[j] = bn_b[col];
        }
    }
    #pragma unroll
    for (int i = 0; i < 8; ++i) {
        const int row = row0 + ((i < 4) ? (ty*4 + i) : (64 + ty*4 + i - 4));
        float v[8];
        #pragma unroll
        for (int j = 0; j < 8; ++j) {
            v[j] = acc[i][j] + bi[j];
            if (BNRELU) {
                float p = (v[j] - mu[j]) * sc[j];
                asm volatile("" : "+v"(p));
                v[j] = fmaxf(p + be[j], 0.0f);
            }
        }
        float* cp = C + (size_t)z * sC + (size_t)row * Hc + col0;
        *(float4*)(cp + tx*4)      = *(const float4*)&v[0];
        *(float4*)(cp + 64 + tx*4) = *(const float4*)&v[4];
    }
}

// ---- row-wise sum of squares (numpy 8-accumulator pairwise) ----
__global__ __launch_bounds__(256) void rowsq_np(const float* __restrict__ X,
                                                float* __restrict__ out, int rows)
{
    const int r = blockIdx.x * blockDim.x + threadIdx.x;
    if (r >= rows) return;
    const float* p = X + (size_t)r * C_DIM;
    float rr[8];
    #pragma unroll
    for (int j = 0; j < 8; ++j) {
        float v = p[j]; float s2 = v * v;
        asm volatile("" : "+v"(s2));
        rr[j] = s2;
    }
    for (int i = 8; i < C_DIM; i += 8) {
        #pragma unroll
        for (int j = 0; j < 8; ++j) {
            float v = p[i + j]; float s2 = v * v;
            asm volatile("" : "+v"(s2));
            rr[j] = rr[j] + s2;
        }
    }
    out[r] = ((rr[0]+rr[1]) + (rr[2]+rr[3])) + ((rr[4]+rr[5]) + (rr[6]+rr[7]));
}

// ---- split ze rows -> bf16 fragments [m][rt][32 k8][128][8] + zs + eps ----
__global__ __launch_bounds__(256) void split_ze(
    const float* __restrict__ ze, uint16_t* __restrict__ zeAf,
    float* __restrict__ zs, float* __restrict__ eps)
{
    const int m = blockIdx.y;
    const int r = blockIdx.x * 256 + threadIdx.x;
    const size_t g = (size_t)m * N_ROWS + r;
    const float* p = ze + g * C_DIM;
    float a[C_DIM];
    #pragma unroll
    for (int c4 = 0; c4 < C_DIM/4; ++c4) {
        float4 v = *(const float4*)(p + c4*4);
        a[c4*4+0]=v.x; a[c4*4+1]=v.y; a[c4*4+2]=v.z; a[c4*4+3]=v.w;
    }
    {   // zs (numpy 8-acc pairwise) w.r.t. our ze
        float rr[8];
        #pragma unroll
        for (int j = 0; j < 8; ++j) {
            float v = a[j]; float s2 = v*v; asm volatile("" : "+v"(s2)); rr[j]=s2;
        }
        #pragma unroll
        for (int i = 8; i < C_DIM; i += 8)
            #pragma unroll
            for (int j = 0; j < 8; ++j) {
                float v = a[i+j]; float s2 = v*v; asm volatile("" : "+v"(s2));
                rr[j] = rr[j] + s2;
            }
        zs[g] = ((rr[0]+rr[1]) + (rr[2]+rr[3])) + ((rr[4]+rr[5]) + (rr[6]+rr[7]));
    }
    {   // rigorous |approx-exact| bound ~4.6e-5*T, T <= Sabs/2048; use 1e-4
        float sab = 0.0f;
        #pragma unroll
        for (int c = 0; c < C_DIM; ++c) sab += fabsf(a[c]);
        eps[g] = sab * 4.8828125e-4f * 1e-4f + 1e-9f;
    }
    const int rt = r >> 7, rl = r & 127;
    uint16_t* base = zeAf + (size_t)m * 4194304 + ((size_t)rt * 4096 + rl) * 8;
    #pragma unroll
    for (int k8 = 0; k8 < 32; ++k8) {
        uint16_t u[8];
        #pragma unroll
        for (int j = 0; j < 8; ++j) {
            const int c = ((k8 < 16) ? k8 : (k8 - 16)) * 8 + j;
            __hip_bfloat16 h = __float2bfloat16(a[c]);
            if (k8 >= 16) {
                float res = a[c] - __bfloat162float(h);
                h = __float2bfloat16(res);
            }
            u[j] = *(uint16_t*)&h;
        }
        *(float4*)(base + (size_t)k8 * 1024) = *(const float4*)u;
    }
}

// ---- split codebook -> frags; also cbsq (numpy 8-acc) + count=0 ----
__global__ __launch_bounds__(256) void split_cb(
    const float* __restrict__ cb, uint16_t* __restrict__ cbBf,
    float* __restrict__ cbsq, int* __restrict__ count)
{
    const int m = blockIdx.z;
    const int k = blockIdx.x * 256 + threadIdx.x;
    if (m == 0 && k == 0) *count = 0;
    const float* p = cb + ((size_t)m * K_CODES + k) * C_DIM;
    float a[C_DIM];
    #pragma unroll
    for (int c4 = 0; c4 < C_DIM/4; ++c4) {
        float4 v = *(const float4*)(p + c4*4);
        a[c4*4+0]=v.x; a[c4*4+1]=v.y; a[c4*4+2]=v.z; a[c4*4+3]=v.w;
    }
    {
        float rr[8];
        #pragma unroll
        for (int j = 0; j < 8; ++j) {
            float v = a[j]; float s2 = v*v; asm volatile("" : "+v"(s2)); rr[j]=s2;
        }
        #pragma unroll
        for (int i = 8; i < C_DIM; i += 8)
            #pragma unroll
            for (int j = 0; j < 8; ++j) {
                float v = a[i+j]; float s2 = v*v; asm volatile("" : "+v"(s2));
                rr[j] = rr[j] + s2;
            }
        cbsq[(size_t)m * K_CODES + k] =
            ((rr[0]+rr[1]) + (rr[2]+rr[3])) + ((rr[4]+rr[5]) + (rr[6]+rr[7]));
    }
    const int ct = k >> 7, kl = k & 127;
    uint16_t* base = cbBf + (((size_t)m * 16 + ct) * 4096 + kl) * 8;
    #pragma unroll
    for (int k8 = 0; k8 < 32; ++k8) {
        uint16_t u[8];
        #pragma unroll
        for (int j = 0; j < 8; ++j) {
            const int c = ((k8 < 16) ? k8 : (k8 - 16)) * 8 + j;
            __hip_bfloat16 h = __float2bfloat16(a[c]);
            if (k8 >= 16) {
                float res = a[c] - __bfloat162float(h);
                h = __float2bfloat16(res);
            }
            u[j] = *(uint16_t*)&h;
        }
        *(float4*)(base + (size_t)k8 * 1024) = *(const float4*)u;
    }
}

// ---- VQ approx: full-B-in-LDS (64KB), RT=8 row-tiles, T1 swizzle ----
// Defended config (4 failed variants): 128-code B tile amortizes A stream +
// atomics; kb2 funnel + 2 barriers/rt bound register lifetime (no spills);
// no setprio (lockstep structure). Do not perturb without counter evidence.
__global__ __launch_bounds__(256, 2) void vq_mfma(
    const uint16_t* __restrict__ zeAf, const uint16_t* __restrict__ cbBf,
    const float* __restrict__ zs, const float* __restrict__ cbsq,
    unsigned long long* __restrict__ keysB, unsigned long long* __restrict__ keysS)
{
    __shared__ __align__(16) uint16_t Ball[32768];   // 64KB: full (m,ct) B tile
    __shared__ unsigned long long kb2[128][2];

    const int t = threadIdx.x;
    const int l = t & 63, w = t >> 6;
    const int ct = blockIdx.y;
    const int rt0 = (blockIdx.x & 15) * VQ_RT;
    const int m = blockIdx.x >> 4;
    const int lq = l >> 4, lc = l & 15;

    const uint16_t* Bg = cbBf + ((size_t)m * 16 + ct) * 32768;
#ifdef HAVE_GLL
    #pragma unroll
    for (int i = 0; i < 16; ++i)
        gll16(Bg + (size_t)(t + i*256) * 8, Ball + (size_t)(t + i*256) * 8);
#else
    #pragma unroll
    for (int i = 0; i < 16; ++i)
        *(float4*)(Ball + (size_t)(t + i*256)*8) =
            *(const float4*)(Bg + (size_t)(t + i*256)*8);
#endif
    __syncthreads();

    const float* csb = cbsq + (size_t)m * K_CODES + ct*128;

    for (int ri = 0; ri < VQ_RT; ++ri) {
        const int rt = rt0 + ri;
        const uint16_t* Ag = zeAf + (size_t)m * 4194304 + (size_t)rt * 32768;
        f32x4 acc[2][8] = {};
        #pragma unroll
        for (int s = 0; s < 4; ++s) {
            short8v zeh[2], zel[2], cbf[8];
            #pragma unroll
            for (int rc = 0; rc < 2; ++rc) {
                const int row = w*32 + rc*16 + lc;
                zeh[rc] = *(const short8v*)(Ag + ((size_t)(s*4 + lq)*128 + row)*8);
                zel[rc] = *(const short8v*)(Ag + ((size_t)(16 + s*4 + lq)*128 + row)*8);
            }
            #pragma unroll
            for (int c8 = 0; c8 < 8; ++c8)
                cbf[c8] = *(const short8v*)(Ball + ((size_t)(s*4 + lq)*128 + c8*16 + lc)*8);
            #pragma unroll
            for (int rc = 0; rc < 2; ++rc)
                #pragma unroll
                for (int c8 = 0; c8 < 8; ++c8)
                    acc[rc][c8] = __builtin_amdgcn_mfma_f32_16x16x32_bf16(
                        cbf[c8], zeh[rc], acc[rc][c8], 0, 0, 0);   // ze_h*cb_h
            #pragma unroll
            for (int rc = 0; rc < 2; ++rc)
                #pragma unroll
                for (int c8 = 0; c8 < 8; ++c8)
                    acc[rc][c8] = __builtin_amdgcn_mfma_f32_16x16x32_bf16(
                        cbf[c8], zel[rc], acc[rc][c8], 0, 0, 0);   // ze_l*cb_h
            #pragma unroll
            for (int c8 = 0; c8 < 8; ++c8)
                cbf[c8] = *(const short8v*)(Ball + ((size_t)(16 + s*4 + lq)*128 + c8*16 + lc)*8);
            #pragma unroll
            for (int rc = 0; rc < 2; ++rc)
                #pragma unroll
                for (int c8 = 0; c8 < 8; ++c8)
                    acc[rc][c8] = __builtin_amdgcn_mfma_f32_16x16x32_bf16(
                        cbf[c8], zeh[rc], acc[rc][c8], 0, 0, 0);   // ze_h*cb_l
        }

        // lane-local float top-2 over 32 codes, 2-step 4-lane butterfly
        #pragma unroll
        for (int rc = 0; rc < 2; ++rc) {
            const int row = w*32 + rc*16 + lc;
            float bd = 3.4e38f, sd = 3.4e38f;
            int bidx = 0;
            #pragma unroll
            for (int c8 = 0; c8 < 8; ++c8)
                #pragma unroll
                for (int q = 0; q < 4; ++q) {
                    const int cl = c8*16 + lq*4 + q;
                    const float d = fmaf(-2.0f, acc[rc][c8][q], csb[cl]);
                    const float mx = fmaxf(bd, d);
                    sd = fminf(sd, mx);
                    if (d < bd) { bd = d; bidx = ct*128 + cl; }
                }
            #pragma unroll
            for (int mk = 16; mk < 64; mk <<= 1) {
                const float ob = __shfl_xor(bd, mk);
                const int   oi = __shfl_xor(bidx, mk);
                const float os = __shfl_xor(sd, mk);
                const float mx = fmaxf(bd, ob);
                sd = fminf(fminf(sd, os), mx);
                if (ob < bd) { bd = ob; bidx = oi; }
            }
            if (lq == 0) {
                kb2[row][0] = ((unsigned long long)mapmono(bd) << 32) | (unsigned)bidx;
                kb2[row][1] = ((unsigned long long)mapmono(sd) << 32) | 0xFFFFFFFFu;
            }
        }
        __syncthreads();
        if (t < 128) {
            const unsigned long long b = kb2[t][0];
            const unsigned long long s2v = kb2[t][1];
            const size_t g = (size_t)m * N_ROWS + (size_t)rt*128 + t;
            const unsigned long long old = atomicMin(&keysB[g], b);
            const unsigned long long disp = (b < old) ? old : b;
            const unsigned long long cand = (s2v < disp) ? s2v : disp;
            atomicMin(&keysS[g], cand);
        }
        __syncthreads();   // protect kb2 before next rt
    }
}

// ---- flag: near-tie only (rigorous bound makes exact-dot check redundant) ----
__global__ __launch_bounds__(256) void vq_flag(
    unsigned long long* __restrict__ keysB,
    const unsigned long long* __restrict__ keysS,
    const float* __restrict__ eps, int* __restrict__ list, int* __restrict__ count)
{
    const int m = blockIdx.y;
    const int r = blockIdx.x * 256 + threadIdx.x;
    const size_t g = (size_t)m * N_ROWS + r;
    const float db = unmapmono((unsigned int)(keysB[g] >> 32));
    const float ds2 = unmapmono((unsigned int)(keysS[g] >> 32));
    if (ds2 - db <= 2.0f * eps[g]) {
        keysB[g] = ~0ull;                 // cleanup owns this row now
        const int p = atomicAdd(count, 1);
        list[p] = (int)g;
    }
}

// ---- exact cleanup v3: (row, 1/8-code-slice) work items, 1 code/thread ----
__global__ __launch_bounds__(256) void vq_cleanup3(
    const float* __restrict__ ze, const float* __restrict__ cb,
    const float* __restrict__ zs, const float* __restrict__ cbsq,
    const int* __restrict__ list, const int* __restrict__ count,
    unsigned long long* __restrict__ keysB)
{
    __shared__ float zrow[C_DIM];
    __shared__ unsigned long long red[4];
    const int t = threadIdx.x;
    const int w = t >> 6, l = t & 63;
    const int ntot = (*count) * 8;
    for (int wi = blockIdx.x; wi < ntot; wi += gridDim.x) {
        const int idx = wi >> 3, ks = wi & 7;
        const int g = list[idx];
        const int m = g >> 14;
        __syncthreads();   // zrow reuse guard
        if (t < 32)
            *(float4*)(zrow + t*4) = *(const float4*)(ze + (size_t)g * C_DIM + t*4);
        __syncthreads();
        const float zsr = zs[g];
        const int code = ks * 256 + t;
        const float* cbp = cb + ((size_t)m * K_CODES + code) * C_DIM;
        float acc = 0.0f;
        #pragma unroll
        for (int c4 = 0; c4 < C_DIM/4; ++c4) {
            const float4 b4 = *(const float4*)(cbp + c4*4);
            acc = fmaf(zrow[c4*4+0], b4.x, acc);
            acc = fmaf(zrow[c4*4+1], b4.y, acc);
            acc = fmaf(zrow[c4*4+2], b4.z, acc);
            acc = fmaf(zrow[c4*4+3], b4.w, acc);
        }
        const float tmp = zsr + cbsq[(size_t)m * K_CODES + code];
        float m2a = 2.0f * acc;
        asm volatile("" : "+v"(m2a));
        const float d = tmp - m2a;
        unsigned long long key =
            ((unsigned long long)mapmono(d) << 32) | (unsigned)code;
        #pragma unroll
        for (int off2 = 32; off2 > 0; off2 >>= 1) {
            const unsigned long long o = __shfl_down(key, off2);
            key = (o < key) ? o : key;
        }
        if (l == 0) red[w] = key;
        __syncthreads();
        if (t == 0) {
            unsigned long long b = red[0];
            b = (red[1] < b) ? red[1] : b;
            b = (red[2] < b) ? red[2] : b;
            b = (red[3] < b) ? red[3] : b;
            atomicMin(&keysB[g], b);
        }
    }
}

// ---- split weights W[(m)][Kd][Hc] -> frags [m][Hc/64][Kd/4][64][8] ----
__global__ __launch_bounds__(256) void split_wB(
    const float* __restrict__ W, uint16_t* __restrict__ Wf, int Kd, int Hc)
{
    const int z = blockIdx.z;
    W += (size_t)z * Kd * Hc;
    Wf += (size_t)z * Kd * Hc * 2;
    const int ct = blockIdx.x, k8 = blockIdx.y;
    const int Sh = Kd / 8, S = Kd / 4;
    const int t = threadIdx.x;
    #pragma unroll
    for (int e0 = 0; e0 < 2; ++e0) {
        const int e = t + e0 * 256;
        const int h = e >> 3, j = e & 7;
        const float v = W[(size_t)(k8*8 + j) * Hc + ct*64 + h];
        __hip_bfloat16 hi = __float2bfloat16(v);
        float res = v - __bfloat162float(hi);
        __hip_bfloat16 lo = __float2bfloat16(res);
        Wf[(((size_t)ct*S + k8)*64 + h)*8 + j]      = *(uint16_t*)&hi;
        Wf[(((size_t)ct*S + Sh + k8)*64 + h)*8 + j] = *(uint16_t*)&lo;
    }
}

// ---- strided/batched GEMM via split-bf16 MFMA (A fp32 split inline) ----
template<bool BNRELU>
__global__ __launch_bounds__(256, 3) void mfma_fused(
    const float* __restrict__ A, const uint16_t* __restrict__ Wf,
    const float* __restrict__ bias, const float* __restrict__ bn_g,
    const float* __restrict__ bn_b, const float* __restrict__ bn_m,
    const float* __restrict__ bn_v, float* __restrict__ C, int Kd, int Hc,
    size_t sA, size_t sWf, size_t sP, size_t sC)
{
    __shared__ __align__(16) uint16_t Ah[4096], Al[4096], Bh[2048], Bl[2048];
    const int z = blockIdx.z;
    A += (size_t)z * sA; Wf += (size_t)z * sWf; bias += (size_t)z * sP;
    if (BNRELU) {
        bn_g += (size_t)z * sP; bn_b += (size_t)z * sP;
        bn_m += (size_t)z * sP; bn_v += (size_t)z * sP;
    }
    C += (size_t)z * sC;

    const int t = threadIdx.x;
    const int l = t & 63, w = t >> 6;
    const int kq = l >> 4, lc = l & 15;
    const int row0 = blockIdx.y * 128, col0 = blockIdx.x * 64;
    const int Sh = Kd / 8, S = Kd / 4;
    const uint16_t* Wct = Wf + (size_t)blockIdx.x * S * 512;

    f32x4 acc[2][4] = {};
    const int arow = t & 127, khalf = t >> 7;
    for (int ks = 0; ks < Kd / 32; ++ks) {
        const float* ap = A + (size_t)(row0 + arow) * Kd + ks*32 + khalf*16;
        float fa[16];
        *(float4*)&fa[0]  = *(const float4*)(ap);
        *(float4*)&fa[4]  = *(const float4*)(ap + 4);
        *(float4*)&fa[8]  = *(const float4*)(ap + 8);
        *(float4*)&fa[12] = *(const float4*)(ap + 12);
        uint16_t ah[16], al16[16];
        #pragma unroll
        for (int i = 0; i < 16; ++i) {
            __hip_bfloat16 h = __float2bfloat16(fa[i]);
            float res = fa[i] - __bfloat162float(h);
            __hip_bfloat16 lo = __float2bfloat16(res);
            ah[i] = *(uint16_t*)&h; al16[i] = *(uint16_t*)&lo;
        }
        #pragma unroll
        for (int kql = 0; kql < 2; ++kql) {
            const int kq_ = khalf*2 + kql;
            *(float4*)(Ah + ((size_t)kq_*128 + arow)*8) = *(const float4*)&ah[kql*8];
            *(float4*)(Al + ((size_t)kq_*128 + arow)*8) = *(const float4*)&al16[kql*8];
        }
        {
            const int sec = t >> 6, off = (t & 63) * 8;
            *(float4*)(Bh + (size_t)sec*512 + off) =
                *(const float4*)(Wct + ((size_t)(ks*4 + sec))*512 + off);
            *(float4*)(Bl + (size_t)sec*512 + off) =
                *(const float4*)(Wct + ((size_t)(Sh + ks*4 + sec))*512 + off);
        }
        __syncthreads();
        short8v afh[2], afl[2], bfh[4], bfl[4];
        #pragma unroll
        for (int r2 = 0; r2 < 2; ++r2) {
            afh[r2] = *(const short8v*)(Ah + ((size_t)kq*128 + w*32 + r2*16 + lc)*8);
            afl[r2] = *(const short8v*)(Al + ((size_t)kq*128 + w*32 + r2*16 + lc)*8);
        }
        #pragma unroll
        for (int c4 = 0; c4 < 4; ++c4) {
            bfh[c4] = *(const short8v*)(Bh + ((size_t)kq*64 + c4*16 + lc)*8);
            bfl[c4] = *(const short8v*)(Bl + ((size_t)kq*64 + c4*16 + lc)*8);
        }
        #pragma unroll
        for (int r2 = 0; r2 < 2; ++r2)
            #pragma unroll
            for (int c4 = 0; c4 < 4; ++c4) {
                acc[r2][c4] = __builtin_amdgcn_mfma_f32_16x16x32_bf16(
                    afh[r2], bfh[c4], acc[r2][c4], 0, 0, 0);
                acc[r2][c4] = __builtin_amdgcn_mfma_f32_16x16x32_bf16(
                    afl[r2], bfh[c4], acc[r2][c4], 0, 0, 0);
                acc[r2][c4] = __builtin_amdgcn_mfma_f32_16x16x32_bf16(
                    afh[r2], bfl[c4], acc[r2][c4], 0, 0, 0);
            }
        __syncthreads();
    }
    #pragma unroll
    for (int c4 = 0; c4 < 4; ++c4) {
        const int col = col0 + c4*16 + lc;
        const float bi = bias[col];
        float sc = 0.f, mu = 0.f, be = 0.f;
        if (BNRELU) {
            sc = bn_g[col] / sqrtf(bn_v[col] + EPS_V);
            mu = bn_m[col]; be = bn_b[col];
        }
        #pragma unroll
        for (int r2 = 0; r2 < 2; ++r2)
            #pragma unroll
            for (int q = 0; q < 4; ++q) {
                const int row = row0 + w*32 + r2*16 + kq*4 + q;
                float v = acc[r2][c4][q] + bi;
                if (BNRELU) v = fmaxf((v - mu) * sc + be, 0.0f);
                C[(size_t)row * Hc + col] = v;
            }
    }
}

// ---- old exact tiled VQ (round-5) — fallback when ws too small ----
__global__ __launch_bounds__(256, 4) void vq_argmin(
    const float* __restrict__ ze, const float* __restrict__ cb,
    const float* __restrict__ ze_sq, const float* __restrict__ cb_sq,
    unsigned long long* __restrict__ keys)
{
    __shared__ __align__(16) char smem_raw[32768];
    float* As = (float*)smem_raw;
    float* Bs = As + 32*128;
    unsigned long long* kb = (unsigned long long*)smem_raw;
    const int m = blockIdx.z;
    const float* Zm  = ze + (size_t)m * N_ROWS * C_DIM;
    const float* Bm  = cb + (size_t)m * K_CODES * C_DIM;
    const float* zsm = ze_sq + (size_t)m * N_ROWS;
    const float* csm = cb_sq + (size_t)m * K_CODES;
    const int t = threadIdx.x;
    const int tx = t & 15, ty = t >> 4;
    const int row0 = blockIdx.y * 128, col0 = blockIdx.x * 128;
    const int ar = t & 127, ak = (t >> 7) * 4;
    float acc[8][8] = {};
    for (int k0 = 0; k0 < C_DIM; k0 += 32) {
        #pragma unroll
        for (int l = 0; l < 4; ++l) {
            const int lk = ak + l * 8;
            float4 av = *(const float4*)(Zm + (size_t)(row0 + ar) * C_DIM + (k0 + lk));
            As[(lk+0)*128+ar] = av.x; As[(lk+1)*128+ar] = av.y;
            As[(lk+2)*128+ar] = av.z; As[(lk+3)*128+ar] = av.w;
            float4 bv = *(const float4*)(Bm + (size_t)(col0 + ar) * C_DIM + (k0 + lk));
            Bs[(lk+0)*128+ar] = bv.x; Bs[(lk+1)*128+ar] = bv.y;
            Bs[(lk+2)*128+ar] = bv.z; Bs[(lk+3)*128+ar] = bv.w;
        }
        __syncthreads();
        #pragma unroll
        for (int kk = 0; kk < 32; ++kk) {
            float a[8], b[8];
            *(float4*)&a[0] = *(const float4*)&As[kk*128 + ty*4];
            *(float4*)&a[4] = *(const float4*)&As[kk*128 + 64 + ty*4];
            *(float4*)&b[0] = *(const float4*)&Bs[kk*128 + tx*4];
            *(float4*)&b[4] = *(const float4*)&Bs[kk*128 + 64 + tx*4];
            #pragma unroll
            for (int i = 0; i < 8; ++i)
                #pragma unroll
                for (int j = 0; j < 8; ++j)
                    acc[i][j] = fmaf(a[i], b[j], acc[i][j]);
        }
        __syncthreads();
    }
    unsigned long long mykey[8];
    #pragma unroll
    for (int i = 0; i < 8; ++i) {
        const int rloc = (i < 4) ? (ty*4 + i) : (64 + ty*4 + i - 4);
        const float zsv = zsm[row0 + rloc];
        unsigned long long bk = ~0ull;
        #pragma unroll
        for (int j = 0; j < 8; ++j) {
            const int code = col0 + ((j < 4) ? (tx*4 + j) : (64 + tx*4 + j - 4));
            const float d = (zsv + csm[code]) - 2.0f * acc[i][j];
            const unsigned long long key =
                ((unsigned long long)mapmono(d) << 32) | (unsigned)code;
            bk = (key < bk) ? key : bk;
        }
        mykey[i] = bk;
    }
    __syncthreads();
    #pragma unroll
    for (int i = 0; i < 8; ++i) {
        const int rloc = (i < 4) ? (ty*4 + i) : (64 + ty*4 + i - 4);
        kb[rloc*17 + tx] = mykey[i];
    }
    __syncthreads();
    if (t < 128) {
        unsigned long long bk = kb[t*17];
        #pragma unroll
        for (int k2 = 1; k2 < 16; ++k2) {
            const unsigned long long k = kb[t*17 + k2];
            bk = (k < bk) ? k : bk;
        }
        atomicMin(&keys[(size_t)m * N_ROWS + row0 + t], bk);
    }
}

// ---- gather chosen codes: ce (fp32 out) + zq = sum_m ce ----
__global__ __launch_bounds__(256) void gather_ce_zq(
    const unsigned long long* __restrict__ keys, const float* __restrict__ cb,
    float* __restrict__ ce_out, float* __restrict__ zq)
{
    const int gid = blockIdx.x * 256 + threadIdx.x;
    const int n = gid >> 7, c = gid & 127;
    float s = 0.0f;
    #pragma unroll
    for (int m = 0; m < M_BOOKS; ++m) {
        const int idx = (int)(keys[(size_t)m * N_ROWS + n] & 0xFFFFFFFFull);
        const float v = cb[((size_t)m * K_CODES + idx) * C_DIM + c];
        ce_out[((size_t)m * N_ROWS + n) * (size_t)C_DIM + c] = v;
        s += v;
    }
    zq[gid] = s;
}

extern "C" void kernel_launch(void* const* d_in, const int* in_sizes, int n_in,
                              void* d_out, int out_size, void* d_ws, size_t ws_size,
                              hipStream_t stream)
{
    const float* x   = (const float*)d_in[0];
    const float* eW1 = (const float*)d_in[1];
    const float* eb1 = (const float*)d_in[2];
    const float* g1  = (const float*)d_in[3];
    const float* b1  = (const float*)d_in[4];
    const float* m1  = (const float*)d_in[5];
    const float* v1  = (const float*)d_in[6];
    const float* eW2 = (const float*)d_in[7];
    const float* eb2 = (const float*)d_in[8];
    const float* g2  = (const float*)d_in[9];
    const float* b2  = (const float*)d_in[10];
    const float* m2  = (const float*)d_in[11];
    const float* v2  = (const float*)d_in[12];
    const float* eW3 = (const float*)d_in[13];
    const float* eb3 = (const float*)d_in[14];
    const float* cb  = (const float*)d_in[15];
    const float* dW1 = (const float*)d_in[16];
    const float* db1 = (const float*)d_in[17];
    const float* dg1 = (const float*)d_in[18];
    const float* dbb1= (const float*)d_in[19];
    const float* dm1 = (const float*)d_in[20];
    const float* dv1 = (const float*)d_in[21];
    const float* dW2 = (const float*)d_in[22];
    const float* db2 = (const float*)d_in[23];
    const float* dg2 = (const float*)d_in[24];
    const float* dbb2= (const float*)d_in[25];
    const float* dm2 = (const float*)d_in[26];
    const float* dv2 = (const float*)d_in[27];
    const float* dW3 = (const float*)d_in[28];
    const float* db3 = (const float*)d_in[29];

    float* out_xhat = (float*)d_out;
    float* out_ze   = out_xhat + (size_t)N_ROWS * E_DIM;
    float* out_ce   = out_ze + (size_t)M_BOOKS * N_ROWS * C_DIM;

    float* ws = (float*)d_ws;
    const size_t h1N1 = (size_t)N_ROWS * H1_DIM;
    const size_t h2N1 = (size_t)N_ROWS * H2_DIM;

    // floats needed by batched VQ + all weight-frag machinery
    const size_t vqNeedF = 8192 + 65536 + 65536 + 8388608 + 1048576
                         + 131072 + 131072 + 65536 + 16
                         + 32768 + 32768 + 65536
                         + 524288 + 131072 + 131072;
    const bool tierA = ws_size >= ((size_t)M_BOOKS*(h1N1+h2N1) + vqNeedF + 64) * 4;
    const bool tierB = ws_size >= ((h1N1+h2N1) + vqNeedF + 64) * 4;

    dim3 blk(256, 1, 1);

    if (tierB) {
        size_t off = 0;
        float* h1 = ws; off += (tierA ? M_BOOKS : 1) * h1N1;
        float* h2 = ws + off; off += (tierA ? M_BOOKS : 1) * h2N1;
        float* cbsq = ws + off; off += 8192;
        float* zsb = ws + off; off += 65536;
        float* epsb = ws + off; off += 65536;
        uint16_t* zeAf = (uint16_t*)(ws + off); off += 8388608;
        uint16_t* cbBf = (uint16_t*)(ws + off); off += 1048576;
        unsigned long long* keysB = (unsigned long long*)(ws + off); off += 131072;
        unsigned long long* keysS = (unsigned long long*)(ws + off); off += 131072;
        int* list = (int*)(ws + off); off += 65536;
        int* count = (int*)(ws + off); off += 16;
        uint16_t* w1f = (uint16_t*)(ws + off); off += 32768;
        uint16_t* w2f = (uint16_t*)(ws + off); off += 32768;
        uint16_t* w3f = (uint16_t*)(ws + off); off += 65536;
        uint16_t* we1f = (uint16_t*)(ws + off); off += 524288;
        uint16_t* we2f = (uint16_t*)(ws + off); off += 131072;
        uint16_t* we3f = (uint16_t*)(ws + off); off += 131072;
        float* zq = h1; float* d1 = h2; float* d2 = h1;

        // prep (independent of encoders)
        split_cb<<<dim3(K_CODES/256, 1, M_BOOKS), blk, 0, stream>>>(cb, cbBf, cbsq, count);
        split_wB<<<dim3(H1_DIM/64, E_DIM/8, M_BOOKS), blk, 0, stream>>>(eW1, we1f, E_DIM, H1_DIM);
        split_wB<<<dim3(H2_DIM/64, H1_DIM/8, M_BOOKS), blk, 0, stream>>>(eW2, we2f, H1_DIM, H2_DIM);
        split_wB<<<dim3(C_DIM/64, H2_DIM/8, M_BOOKS), blk, 0, stream>>>(eW3, we3f, H2_DIM, C_DIM);
        split_wB<<<dim3(H2_DIM/64, C_DIM/8, 1), blk, 0, stream>>>(dW1, w1f, C_DIM, H2_DIM);
        split_wB<<<dim3(H1_DIM/64, H2_DIM/8, 1), blk, 0, stream>>>(dW2, w2f, H2_DIM, H1_DIM);
        split_wB<<<dim3(E_DIM/64, H1_DIM/8, 1), blk, 0, stream>>>(dW3, w3f, H1_DIM, E_DIM);
        hipMemsetAsync((void*)keysB, 0xFF, (size_t)M_BOOKS * N_ROWS * 8 * 2, stream);

        const int nz = tierA ? M_BOOKS : 1;
        const int nloop = tierA ? 1 : M_BOOKS;
        for (int p = 0; p < nloop; ++p) {
            const size_t mb = tierA ? 0 : (size_t)p;
            mfma_fused<true><<<dim3(H1_DIM/64, N_ROWS/128, nz), blk, 0, stream>>>(
                x, we1f + mb*(size_t)E_DIM*H1_DIM*2,
                eb1 + mb*H1_DIM, g1 + mb*H1_DIM, b1 + mb*H1_DIM, m1 + mb*H1_DIM, v1 + mb*H1_DIM,
                h1, E_DIM, H1_DIM,
                0, (size_t)E_DIM*H1_DIM*2, H1_DIM, h1N1);
            mfma_fused<true><<<dim3(H2_DIM/64, N_ROWS/128, nz), blk, 0, stream>>>(
                h1, we2f + mb*(size_t)H1_DIM*H2_DIM*2,
                eb2 + mb*H2_DIM, g2 + mb*H2_DIM, b2 + mb*H2_DIM, m2 + mb*H2_DIM, v2 + mb*H2_DIM,
                h2, H1_DIM, H2_DIM,
                h1N1, (size_t)H1_DIM*H2_DIM*2, H2_DIM, h2N1);
            mfma_fused<false><<<dim3(C_DIM/64, N_ROWS/128, nz), blk, 0, stream>>>(
                h2, we3f + mb*(size_t)H2_DIM*C_DIM*2,
                eb3 + mb*C_DIM, nullptr, nullptr, nullptr, nullptr,
                out_ze + mb*(size_t)N_ROWS*C_DIM, H2_DIM, C_DIM,
                h2N1, (size_t)H2_DIM*C_DIM*2, C_DIM, (size_t)N_ROWS*C_DIM);
        }

        split_ze<<<dim3(N_ROWS/256, M_BOOKS), blk, 0, stream>>>(out_ze, zeAf, zsb, epsb);
        vq_mfma<<<dim3(16 * M_BOOKS, K_CODES/128, 1), blk, 0, stream>>>(
            zeAf, cbBf, zsb, cbsq, keysB, keysS);
        vq_flag<<<dim3(N_ROWS/256, M_BOOKS), blk, 0, stream>>>(
            keysB, keysS, epsb, list, count);
        vq_cleanup3<<<dim3(2048), blk, 0, stream>>>(
            out_ze, cb, zsb, cbsq, list, count, keysB);

        gather_ce_zq<<<dim3((N_ROWS*C_DIM)/256), blk, 0, stream>>>(keysB, cb, out_ce, zq);
        mfma_fused<true><<<dim3(H2_DIM/64, N_ROWS/128, 1), blk, 0, stream>>>(
            zq, w1f, db1, dg1, dbb1, dm1, dv1, d1, C_DIM, H2_DIM, 0, 0, 0, 0);
        mfma_fused<true><<<dim3(H1_DIM/64, N_ROWS/128, 1), blk, 0, stream>>>(
            d1, w2f, db2, dg2, dbb2, dm2, dv2, d2, H2_DIM, H1_DIM, 0, 0, 0, 0);
        mfma_fused<false><<<dim3(E_DIM/64, N_ROWS/128, 1), blk, 0, stream>>>(
            d2, w3f, db3, nullptr, nullptr, nullptr, nullptr,
            out_xhat, H1_DIM, E_DIM, 0, 0, 0, 0);
        return;
    }

    // ---- fallback: round-5 exact path ----
    {
        const size_t smallN = (size_t)M_BOOKS*N_ROWS + (size_t)M_BOOKS*K_CODES
                            + 2 + 2*(size_t)M_BOOKS*N_ROWS;
        const size_t fullFloats = (size_t)M_BOOKS*(h1N1 + h2N1) + smallN;
        const bool fM = ws_size >= fullFloats * sizeof(float) + 256;
        size_t off = 0;
        float* h1 = ws; off += (fM ? M_BOOKS : 1) * h1N1;
        float* h2 = ws + off; off += (fM ? M_BOOKS : 1) * h2N1;
        float* zesq = ws + off; off += (size_t)M_BOOKS * N_ROWS;
        float* cbsq = ws + off; off += (size_t)M_BOOKS * K_CODES;
        off = (off + 1) & ~(size_t)1;
        unsigned long long* keys = (unsigned long long*)(ws + off);
        float* zq = h1; float* d1 = h2; float* d2 = h1;
        hipMemsetAsync((void*)keys, 0xFF, (size_t)M_BOOKS * N_ROWS * 8, stream);
        const int nz = fM ? M_BOOKS : 1;
        const int nloop = fM ? 1 : M_BOOKS;
        for (int p = 0; p < nloop; ++p) {
            const size_t mb = fM ? 0 : (size_t)p;
            gemm128<32, true><<<dim3(H1_DIM/128, N_ROWS/128, nz), blk, 0, stream>>>(
                x, eW1 + mb*(size_t)E_DIM*H1_DIM,
                eb1 + mb*H1_DIM, g1 + mb*H1_DIM, b1 + mb*H1_DIM, m1 + mb*H1_DIM, v1 + mb*H1_DIM,
                h1, E_DIM, H1_DIM, 0, (size_t)E_DIM*H1_DIM, H1_DIM, h1N1);
            gemm128<32, true><<<dim3(H2_DIM/128, N_ROWS/128, nz), blk, 0, stream>>>(
                h1, eW2 + mb*(size_t)H1_DIM*H2_DIM,
                eb2 + mb*H2_DIM, g2 + mb*H2_DIM, b2 + mb*H2_DIM, m2 + mb*H2_DIM, v2 + mb*H2_DIM,
                h2, H1_DIM, H2_DIM, h1N1, (size_t)H1_DIM*H2_DIM, H2_DIM, h2N1);
            gemm128<32, false><<<dim3(C_DIM/128, N_ROWS/128, nz), blk, 0, stream>>>(
                h2, eW3 + mb*(size_t)H2_DIM*C_DIM,
                eb3 + mb*C_DIM, nullptr, nullptr, nullptr, nullptr,
                out_ze + mb*(size_t)N_ROWS*C_DIM, H2_DIM, C_DIM,
                h2N1, (size_t)H2_DIM*C_DIM, C_DIM, (size_t)N_ROWS*C_DIM);
        }
        rowsq_np<<<dim3((M_BOOKS*N_ROWS)/256), blk, 0, stream>>>(out_ze, zesq, M_BOOKS*N_ROWS);
        rowsq_np<<<dim3((M_BOOKS*K_CODES)/256), blk, 0, stream>>>(cb, cbsq, M_BOOKS*K_CODES);
        vq_argmin<<<dim3(K_CODES/128, N_ROWS/128, M_BOOKS), blk, 0, stream>>>(
            out_ze, cb, zesq, cbsq, keys);
        gather_ce_zq<<<dim3((N_ROWS*C_DIM)/256), blk, 0, stream>>>(keys, cb, out_ce, zq);
        gemm128<32, true><<<dim3(H2_DIM/128, N_ROWS/128, 1), blk, 0, stream>>>(
            zq, dW1, db1, dg1, dbb1, dm1, dv1, d1, C_DIM, H2_DIM, 0, 0, 0, 0);
        gemm128<32, true><<<dim3(H1_DIM/128, N_ROWS/128, 1), blk, 0, stream>>>(
            d1, dW2, db2, dg2, dbb2, dm2, dv2, d2, H2_DIM, H1_DIM, 0, 0, 0, 0);
        gemm128<32, false><<<dim3(E_DIM/128, N_ROWS/128, 1), blk, 0, stream>>>(
            d2, dW3, db3, nullptr, nullptr, nullptr, nullptr,
            out_xhat, H1_DIM, E_DIM, 0, 0, 0, 0);
    }
}